// Round 3
// baseline (730.055 us; speedup 1.0000x reference)
//
#include <hip/hip_runtime.h>
#include <hip/hip_bf16.h>
#include <math.h>

typedef unsigned short u16;
typedef unsigned int   u32;
typedef _Float16 f16x8 __attribute__((ext_vector_type(8)));
typedef float f32x4  __attribute__((ext_vector_type(4)));

#define Bb 32
#define Tt 2048
#define Ee 1024
#define Mm (Bb*Tt)
// LDS row stride in u16 elements (80 bytes): 16B-aligned frag reads; group
// index (5c+q)&7 spreads 64 lanes 2-per-bank-group (free, m136).
#define LSTR 40

__device__ __forceinline__ float tanh_fast(float x) {
  float ax = fminf(fabsf(x), 15.0f);
  float e  = __expf(2.0f * ax);
  float t  = 1.0f - 2.0f / (e + 1.0f);
  return copysignf(t, x);
}

__device__ __forceinline__ u32 pack2h(float a, float b) {
  _Float16 ha = (_Float16)a, hb = (_Float16)b;   // v_cvt_f16_f32 (RTN)
  return (u32)__builtin_bit_cast(u16, ha) | ((u32)__builtin_bit_cast(u16, hb) << 16);
}

// ---------------- K0: W (K x N fp32) -> Wt_hi/Wt_lo (N x K fp16 split) ----------------
__global__ __launch_bounds__(256) void wt_convert(const float* __restrict__ W,
                                                  u16* __restrict__ Wt_hi,
                                                  u16* __restrict__ Wt_lo) {
  __shared__ float tile[32][33];
  int n0 = blockIdx.x * 32, k0 = blockIdx.y * 32;
  int tx = threadIdx.x, ty = threadIdx.y;   // 32 x 8
#pragma unroll
  for (int i = 0; i < 4; ++i)
    tile[ty + 8*i][tx] = W[(size_t)(k0 + ty + 8*i) * Ee + n0 + tx];
  __syncthreads();
#pragma unroll
  for (int i = 0; i < 4; ++i) {
    float v = tile[tx][ty + 8*i];
    _Float16 hi = (_Float16)v;
    float rem = v - (float)hi;
    _Float16 lo = (_Float16)rem;
    size_t idx = (size_t)(n0 + ty + 8*i) * Ee + k0 + tx;
    Wt_hi[idx] = __builtin_bit_cast(u16, hi);
    Wt_lo[idx] = __builtin_bit_cast(u16, lo);
  }
}

// ---------------- K1: ht = tanh(enc@W + b), fused score = ctx . ht ----------------
// 128x128 tile, BK=32, 4 waves x (4x4 of mfma_f32_16x16x32_f16),
// 2-pass: acc += A_f16 * Whi + A_f16 * Wlo   (W split exact to ~2^-21)
// Software-pipelined: tile kt+1's global loads issue after barrier 2 of tile kt.
__global__ __launch_bounds__(256, 2) void gemm_tanh_score(
    const float* __restrict__ enc, const float* __restrict__ ctx,
    const float* __restrict__ bias,
    const u16* __restrict__ Wt_hi, const u16* __restrict__ Wt_lo,
    u16* __restrict__ ht, float* __restrict__ scores) {
  __shared__ u16 Ahf[128*LSTR], Bhi[128*LSTR], Blo[128*LSTR];   // 30 KB

  // XCD-aware swizzle: XCD = bx%8 (round-robin dispatch). Each XCD owns an
  // interleaved M-slab (mt = 8k + xcd) so enc is fetched once device-wide;
  // 8 consecutive blocks per XCD share one A-tile; all of B (4 MB) lives in
  // that XCD's L2.
  int bx = blockIdx.x;
  int x = bx & 7, local = bx >> 3;
  int nt = local & 7;
  int mt = ((local >> 3) << 3) + x;
  int m0 = mt * 128, n0 = nt * 128;
  int tid = threadIdx.x;
  int w = tid >> 6, lane = tid & 63;
  int wm = (w & 1) * 64, wn = (w >> 1) * 64;
  int q = lane >> 4, c = lane & 15;

  f32x4 zero = {0.f, 0.f, 0.f, 0.f};
  f32x4 acc[4][4];
#pragma unroll
  for (int i = 0; i < 4; ++i)
#pragma unroll
    for (int j = 0; j < 4; ++j) acc[i][j] = zero;

  // staging mapping: thread t -> row (t>>1) in [0,128), k-half (t&1)*16
  int ar = tid >> 1, ah = tid & 1;
  const float* Ap  = enc   + (size_t)(m0 + ar) * Ee + ah * 16;
  const u16*   BhP = Wt_hi + (size_t)(n0 + ar) * Ee + ah * 16;
  const u16*   BlP = Wt_lo + (size_t)(n0 + ar) * Ee + ah * 16;
  u16* AW  = &Ahf[ar * LSTR + ah * 16];
  u16* BhW = &Bhi[ar * LSTR + ah * 16];
  u16* BlW = &Blo[ar * LSTR + ah * 16];

  // prologue: load tile 0 into registers
  float4 fA0, fA1, fA2, fA3;
  uint4 vH0, vH1, vL0, vL1;
  {
    const float4* ap = (const float4*)Ap;
    fA0 = ap[0]; fA1 = ap[1]; fA2 = ap[2]; fA3 = ap[3];
    const uint4* bhp = (const uint4*)BhP;
    vH0 = bhp[0]; vH1 = bhp[1];
    const uint4* blp = (const uint4*)BlP;
    vL0 = blp[0]; vL1 = blp[1];
  }

  for (int kt = 0; kt < 32; ++kt) {
    u32 a01 = pack2h(fA0.x, fA0.y), a23 = pack2h(fA0.z, fA0.w);
    u32 a45 = pack2h(fA1.x, fA1.y), a67 = pack2h(fA1.z, fA1.w);
    u32 a89 = pack2h(fA2.x, fA2.y), aAB = pack2h(fA2.z, fA2.w);
    u32 aCD = pack2h(fA3.x, fA3.y), aEF = pack2h(fA3.z, fA3.w);

    __syncthreads();   // previous iteration's frag reads complete
    ((uint4*)AW)[0]  = make_uint4(a01, a23, a45, a67);
    ((uint4*)AW)[1]  = make_uint4(a89, aAB, aCD, aEF);
    ((uint4*)BhW)[0] = vH0; ((uint4*)BhW)[1] = vH1;
    ((uint4*)BlW)[0] = vL0; ((uint4*)BlW)[1] = vL1;
    __syncthreads();   // staging visible

    // prefetch next K-tile; in flight across ds_read + 32 MFMAs
    {
      int kt2 = (kt < 31) ? kt + 1 : 31;   // last iter: re-load hot lines, dead regs
      const float4* ap = (const float4*)(Ap + (size_t)kt2 * 32);
      fA0 = ap[0]; fA1 = ap[1]; fA2 = ap[2]; fA3 = ap[3];
      const uint4* bhp = (const uint4*)(BhP + (size_t)kt2 * 32);
      vH0 = bhp[0]; vH1 = bhp[1];
      const uint4* blp = (const uint4*)(BlP + (size_t)kt2 * 32);
      vL0 = blp[0]; vL1 = blp[1];
    }

    f16x8 aF[4], bH[4], bL[4];
#pragma unroll
    for (int i = 0; i < 4; ++i) {
      int rax = (wm + i * 16 + c) * LSTR + q * 8;
      aF[i] = *(const f16x8*)(&Ahf[rax]);
      int rbx = (wn + i * 16 + c) * LSTR + q * 8;
      bH[i] = *(const f16x8*)(&Bhi[rbx]);
      bL[i] = *(const f16x8*)(&Blo[rbx]);
    }
#pragma unroll
    for (int i = 0; i < 4; ++i)
#pragma unroll
      for (int j = 0; j < 4; ++j) {
        acc[i][j] = __builtin_amdgcn_mfma_f32_16x16x32_f16(aF[i], bH[j], acc[i][j], 0, 0, 0);
        acc[i][j] = __builtin_amdgcn_mfma_f32_16x16x32_f16(aF[i], bL[j], acc[i][j], 0, 0, 0);
      }
  }

  // epilogue: z -> tanh -> store fp16 ht; fused score partial (ctx dot)
  int bidx = m0 >> 11;                   // T = 2048, tile rows share one batch index
  float ctxv[4], biasv[4];
#pragma unroll
  for (int j = 0; j < 4; ++j) {
    int col = n0 + wn + j * 16 + c;
    ctxv[j]  = ctx[bidx * Ee + col];
    biasv[j] = bias[col];
  }
#pragma unroll
  for (int i = 0; i < 4; ++i) {
#pragma unroll
    for (int r = 0; r < 4; ++r) {
      int rowG = m0 + wm + i * 16 + q * 4 + r;   // C/D: row=(lane>>4)*4+reg, col=lane&15
      u16* hrow = ht + (size_t)rowG * Ee + n0 + wn + c;
      float s = 0.f;
#pragma unroll
      for (int j = 0; j < 4; ++j) {
        float h = tanh_fast(acc[i][j][r] + biasv[j]);
        _Float16 hf = (_Float16)h;
        hrow[j * 16] = __builtin_bit_cast(u16, hf);
        s += h * ctxv[j];
      }
      s += __shfl_xor(s, 1); s += __shfl_xor(s, 2);
      s += __shfl_xor(s, 4); s += __shfl_xor(s, 8);
      if (c == 0) atomicAdd(&scores[rowG], s);
    }
  }
}

// ---------------- K2: softmax over T per batch row ----------------
__global__ __launch_bounds__(256) void softmax_t(const float* __restrict__ scores,
                                                 float* __restrict__ at) {
  __shared__ float red[256];
  int b = blockIdx.x, tid = threadIdx.x;
  float v[8];
  float mx = -3.0e38f;
#pragma unroll
  for (int i = 0; i < 8; ++i) {
    v[i] = scores[b * Tt + i * 256 + tid];
    mx = fmaxf(mx, v[i]);
  }
  red[tid] = mx; __syncthreads();
  for (int s = 128; s > 0; s >>= 1) {
    if (tid < s) red[tid] = fmaxf(red[tid], red[tid + s]);
    __syncthreads();
  }
  mx = red[0]; __syncthreads();
  float sum = 0.f;
#pragma unroll
  for (int i = 0; i < 8; ++i) { v[i] = __expf(v[i] - mx); sum += v[i]; }
  red[tid] = sum; __syncthreads();
  for (int s = 128; s > 0; s >>= 1) {
    if (tid < s) red[tid] += red[tid + s];
    __syncthreads();
  }
  float inv = 1.0f / red[0];
#pragma unroll
  for (int i = 0; i < 8; ++i) at[b * Tt + i * 256 + tid] = v[i] * inv;
}

// ---------------- K3: partial[b,tc,e] = sum_{t in chunk} at[b,t] * ht[b,t,e] ----------------
// 1024 blocks (32 b x 32 t-chunks of 64), 256 thr, 4 e-cols/thread, fully coalesced rows.
__global__ __launch_bounds__(256) void weighted_sum(const u16* __restrict__ ht,
                                                    const float* __restrict__ at,
                                                    float* __restrict__ part) {
  __shared__ float ats[64];
  int bx = blockIdx.x;
  int b = bx >> 5, tc = bx & 31;
  int tid = threadIdx.x;
  if (tid < 64) ats[tid] = at[b * Tt + tc * 64 + tid];
  __syncthreads();
  int e0 = tid * 4;
  const u16* base = ht + (size_t)(b * Tt + tc * 64) * Ee + e0;
  float s0 = 0.f, s1 = 0.f, s2 = 0.f, s3 = 0.f;
#pragma unroll 4
  for (int t = 0; t < 64; ++t) {
    float a = ats[t];
    uint2 u = *(const uint2*)(base + (size_t)t * Ee);
    s0 += a * (float)__builtin_bit_cast(_Float16, (u16)(u.x & 0xffff));
    s1 += a * (float)__builtin_bit_cast(_Float16, (u16)(u.x >> 16));
    s2 += a * (float)__builtin_bit_cast(_Float16, (u16)(u.y & 0xffff));
    s3 += a * (float)__builtin_bit_cast(_Float16, (u16)(u.y >> 16));
  }
  float4 out4 = make_float4(s0, s1, s2, s3);
  *(float4*)(part + ((size_t)(b * 32 + tc) * Ee + e0)) = out4;
}

// ---------------- K4: out[b,e] = sum_tc part[b,tc,e] ----------------
__global__ __launch_bounds__(256) void reduce_part(const float* __restrict__ part,
                                                   float* __restrict__ out) {
  int b = blockIdx.x, tid = threadIdx.x;
  float4 s = make_float4(0.f, 0.f, 0.f, 0.f);
#pragma unroll
  for (int tc = 0; tc < 32; ++tc) {
    float4 p = ((const float4*)(part + (size_t)(b * 32 + tc) * Ee))[tid];
    s.x += p.x; s.y += p.y; s.z += p.z; s.w += p.w;
  }
  ((float4*)(out + (size_t)b * Ee))[tid] = s;
}

extern "C" void kernel_launch(void* const* d_in, const int* in_sizes, int n_in,
                              void* d_out, int out_size, void* d_ws, size_t ws_size,
                              hipStream_t stream) {
  const float* enc  = (const float*)d_in[0];
  const float* ctx  = (const float*)d_in[1];
  const float* W    = (const float*)d_in[2];
  const float* bias = (const float*)d_in[3];
  float* out = (float*)d_out;

  char* ws = (char*)d_ws;
  u16* Wt_hi = (u16*)(ws);
  u16* Wt_lo = (u16*)(ws + (size_t)2 * 1024 * 1024);
  u16* ht    = (u16*)(ws + (size_t)4 * 1024 * 1024);
  float* scores = (float*)(ws + (size_t)4 * 1024 * 1024 + (size_t)Mm * Ee * 2);
  float* at     = scores + Mm;
  // part reuses the Wt region (dead after the GEMM): 32*32*1024 fp32 = 4 MB
  float* part   = (float*)ws;
  // total ws use: max(4 MB Wt planes, 4 MB part) + 128 MB ht + 0.5 MB scores/at

  hipMemsetAsync(scores, 0, (size_t)Mm * sizeof(float), stream);

  wt_convert<<<dim3(32, 32), dim3(32, 8), 0, stream>>>(W, Wt_hi, Wt_lo);
  gemm_tanh_score<<<dim3(4096), dim3(256), 0, stream>>>(enc, ctx, bias, Wt_hi, Wt_lo, ht, scores);
  softmax_t<<<dim3(32), dim3(256), 0, stream>>>(scores, at);
  weighted_sum<<<dim3(1024), dim3(256), 0, stream>>>(ht, at, part);
  reduce_part<<<dim3(32), dim3(256), 0, stream>>>(part, out);
}